// Round 6
// baseline (1099.183 us; speedup 1.0000x reference)
//
#include <hip/hip_runtime.h>
#include <hip/hip_fp16.h>

// ---------------------------------------------------------------------------
// GCN 2-layer forward: out = A_hat @ relu(A_hat @ (x@W1) + b1) @ W2 + b2
// A_hat = D^-1/2 (A + I) D^-1/2.
// Edges partitioned into 64-node dst buckets (counting sort, 1 pass).
// Aggregation: one block per bucket, LDS fp32 atomic accumulators -> deep
// MLP, no per-node reductions. Intermediates fp16; fp32 compute.
// ---------------------------------------------------------------------------

#define NPB      64      // nodes per bucket
#define NB_SHIFT 6
#define NBCAP    2048    // max buckets (n <= 131072)

// ---------------- CSC-lite build (bucket partition only) ----------------

__global__ void k_zero(int* __restrict__ p, int m) {
    int i = blockIdx.x * blockDim.x + threadIdx.x;
    if (i < m) p[i] = 0;
}

__global__ __launch_bounds__(256) void k_hist(const int* __restrict__ dst, int E,
                                              int* __restrict__ bcnt, int nb) {
    __shared__ int h[NBCAP];
    for (int i = threadIdx.x; i < nb; i += 256) h[i] = 0;
    __syncthreads();
    int stride = gridDim.x * 256;
    for (int e = blockIdx.x * 256 + threadIdx.x; e < E; e += stride)
        atomicAdd(&h[dst[e] >> NB_SHIFT], 1);
    __syncthreads();
    for (int i = threadIdx.x; i < nb; i += 256)
        if (h[i]) atomicAdd(&bcnt[i], h[i]);
}

// exclusive scan of up to 2048 bucket counts; 1024 threads, 2 elems each.
__global__ __launch_bounds__(1024) void k_scan_nb(const int* __restrict__ bcnt,
                                                  int* __restrict__ bbase,
                                                  int* __restrict__ bcur, int nb) {
    __shared__ int tmp[1024];
    int t = threadIdx.x;
    int i0 = 2 * t, i1 = 2 * t + 1;
    int v0 = (i0 < nb) ? bcnt[i0] : 0;
    int v1 = (i1 < nb) ? bcnt[i1] : 0;
    int s = v0 + v1;
    tmp[t] = s;
    __syncthreads();
    for (int ofs = 1; ofs < 1024; ofs <<= 1) {
        int u = (t >= ofs) ? tmp[t - ofs] : 0;
        __syncthreads();
        if (t >= ofs) tmp[t] += u;
        __syncthreads();
    }
    int excl = tmp[t] - s;
    if (i0 < nb) { bbase[i0] = excl;      bcur[i0] = excl; }
    if (i1 < nb) { bbase[i1] = excl + v0; bcur[i1] = excl + v0; }
    if (t == 1023) bbase[nb] = tmp[1023];
}

// Partition edges into buckets as packed (src | ldst<<17). Grid fixed 1024.
__global__ __launch_bounds__(256) void k_binpass(const int* __restrict__ src,
                                                 const int* __restrict__ dst,
                                                 int* __restrict__ bcur,
                                                 int* __restrict__ pairs,
                                                 int nb, int E, int epb) {
    __shared__ int lh[NBCAP];
    __shared__ int lbase[NBCAP];
    int t = threadIdx.x;
    for (int i = t; i < nb; i += 256) lh[i] = 0;
    __syncthreads();
    int base = blockIdx.x * epb;
    int pk[8], bb[8];
#pragma unroll
    for (int k = 0; k < 8; ++k) {
        int o = k * 256 + t;
        int e = base + o;
        if (o < epb && e < E) {
            int d = dst[e];
            int b = d >> NB_SHIFT;
            bb[k] = b;
            pk[k] = src[e] | ((d & (NPB - 1)) << 17);
            atomicAdd(&lh[b], 1);
        } else bb[k] = -1;
    }
    __syncthreads();
    for (int i = t; i < nb; i += 256) {
        int c = lh[i];
        lbase[i] = c ? atomicAdd(&bcur[i], c) : 0;
        lh[i] = 0;
    }
    __syncthreads();
#pragma unroll
    for (int k = 0; k < 8; ++k) {
        if (bb[k] >= 0) {
            int r = atomicAdd(&lh[bb[k]], 1);
            pairs[lbase[bb[k]] + r] = pk[k];
        }
    }
}

// per-bucket in-degree -> dinv = rsqrt(deg+1)
__global__ __launch_bounds__(256) void k_bucket_deg(const int* __restrict__ pairs,
                                                    const int* __restrict__ bbase,
                                                    float* __restrict__ dinv, int n) {
    __shared__ int deg[NPB];
    int t = threadIdx.x, bid = blockIdx.x;
    if (t < NPB) deg[t] = 0;
    __syncthreads();
    int ebeg = bbase[bid], eend = bbase[bid + 1];
    for (int e = ebeg + t; e < eend; e += 256)
        atomicAdd(&deg[pairs[e] >> 17], 1);
    __syncthreads();
    if (t < NPB) {
        int node = (bid << NB_SHIFT) + t;
        if (node < n) dinv[node] = rsqrtf((float)(deg[t] + 1));
    }
}

// ---------------- helpers ----------------

union pk2 { __half2 h[2]; uint2 u; };

__device__ __forceinline__ void acc8(float* a, uint4 u) {
    __half2 h0 = *(__half2*)&u.x, h1 = *(__half2*)&u.y;
    __half2 h2 = *(__half2*)&u.z, h3 = *(__half2*)&u.w;
    float2 f0 = __half22float2(h0), f1 = __half22float2(h1);
    float2 f2 = __half22float2(h2), f3 = __half22float2(h3);
    atomicAdd(a + 0, f0.x); atomicAdd(a + 1, f0.y);
    atomicAdd(a + 2, f1.x); atomicAdd(a + 3, f1.y);
    atomicAdd(a + 4, f2.x); atomicAdd(a + 5, f2.y);
    atomicAdd(a + 6, f3.x); atomicAdd(a + 7, f3.y);
}

// ---------------- dense layers (fp16 out, register-tiled) ----------------

__global__ __launch_bounds__(256) void k_gemm1_h(const float* __restrict__ x,
                                                 const float* __restrict__ W,
                                                 __half* __restrict__ h, int n,
                                                 const float* __restrict__ dinv) {
    __shared__ float Ws[128 * 64];
    __shared__ float xsT[128 * 64];
    const int tid = threadIdx.x;
    const int row0 = blockIdx.x * 64;
    {
        const float4* Wg = (const float4*)W;
        float4* Wl = (float4*)Ws;
#pragma unroll
        for (int t = 0; t < 8; ++t) Wl[tid + t * 256] = Wg[tid + t * 256];
    }
    {
        int r = tid & 63, g = tid >> 6;
        int row = row0 + r;
        const float4* xr = (const float4*)(x + (size_t)row * 128);
#pragma unroll
        for (int t = 0; t < 8; ++t) {
            int k0 = g * 32 + t * 4;
            float4 v = (row < n) ? xr[k0 >> 2] : make_float4(0.f, 0.f, 0.f, 0.f);
            xsT[(k0 + 0) * 64 + r] = v.x;
            xsT[(k0 + 1) * 64 + r] = v.y;
            xsT[(k0 + 2) * 64 + r] = v.z;
            xsT[(k0 + 3) * 64 + r] = v.w;
        }
    }
    __syncthreads();

    const int tc = tid & 15;
    const int rg = tid >> 4;
    float acc[4][4];
#pragma unroll
    for (int i = 0; i < 4; ++i)
#pragma unroll
        for (int j = 0; j < 4; ++j) acc[i][j] = 0.f;

#pragma unroll 4
    for (int k = 0; k < 128; ++k) {
        float4 a = *(const float4*)&xsT[k * 64 + rg * 4];
        float4 b = *(const float4*)&Ws[k * 64 + tc * 4];
        acc[0][0] += a.x * b.x; acc[0][1] += a.x * b.y; acc[0][2] += a.x * b.z; acc[0][3] += a.x * b.w;
        acc[1][0] += a.y * b.x; acc[1][1] += a.y * b.y; acc[1][2] += a.y * b.z; acc[1][3] += a.y * b.w;
        acc[2][0] += a.z * b.x; acc[2][1] += a.z * b.y; acc[2][2] += a.z * b.z; acc[2][3] += a.z * b.w;
        acc[3][0] += a.w * b.x; acc[3][1] += a.w * b.y; acc[3][2] += a.w * b.z; acc[3][3] += a.w * b.w;
    }

#pragma unroll
    for (int i = 0; i < 4; ++i) {
        int row = row0 + rg * 4 + i;
        if (row < n) {
            float dd = dinv[row];
            pk2 p;
            p.h[0] = __floats2half2_rn(acc[i][0] * dd, acc[i][1] * dd);
            p.h[1] = __floats2half2_rn(acc[i][2] * dd, acc[i][3] * dd);
            *(uint2*)&h[(size_t)row * 64 + tc * 4] = p.u;
        }
    }
}

__global__ __launch_bounds__(256) void k_gemm2_h(const __half* __restrict__ agg,
                                                 const float* __restrict__ W2,
                                                 __half* __restrict__ h2, int n,
                                                 const float* __restrict__ dinv) {
    __shared__ float Ws[64 * 40];
    __shared__ float hsT[64 * 64];
    const int tid = threadIdx.x;
    const int row0 = blockIdx.x * 64;
    {
        const float4* Wg = (const float4*)W2;
        float4* Wl = (float4*)Ws;
        for (int i = tid; i < 640; i += 256) Wl[i] = Wg[i];
    }
    {
        int r = tid & 63, g = tid >> 6;
        int row = row0 + r;
        const __half* ar = agg + (size_t)row * 64;
#pragma unroll
        for (int t = 0; t < 4; ++t) {
            int k0 = g * 16 + t * 4;
            float4 v = make_float4(0.f, 0.f, 0.f, 0.f);
            if (row < n) {
                uint2 u = *(const uint2*)(ar + k0);
                __half2 h0 = *(__half2*)&u.x, h1 = *(__half2*)&u.y;
                float2 f0 = __half22float2(h0), f1 = __half22float2(h1);
                v = make_float4(f0.x, f0.y, f1.x, f1.y);
            }
            hsT[(k0 + 0) * 64 + r] = v.x > 0.f ? v.x : 0.f;
            hsT[(k0 + 1) * 64 + r] = v.y > 0.f ? v.y : 0.f;
            hsT[(k0 + 2) * 64 + r] = v.z > 0.f ? v.z : 0.f;
            hsT[(k0 + 3) * 64 + r] = v.w > 0.f ? v.w : 0.f;
        }
    }
    __syncthreads();

    const int tc = tid & 15;
    const int rg = tid >> 4;
    if (tc < 10) {
        float acc[4][4];
#pragma unroll
        for (int i = 0; i < 4; ++i)
#pragma unroll
            for (int j = 0; j < 4; ++j) acc[i][j] = 0.f;

#pragma unroll 4
        for (int k = 0; k < 64; ++k) {
            float4 a = *(const float4*)&hsT[k * 64 + rg * 4];
            float4 b = *(const float4*)&Ws[k * 40 + tc * 4];
            acc[0][0] += a.x * b.x; acc[0][1] += a.x * b.y; acc[0][2] += a.x * b.z; acc[0][3] += a.x * b.w;
            acc[1][0] += a.y * b.x; acc[1][1] += a.y * b.y; acc[1][2] += a.y * b.z; acc[1][3] += a.y * b.w;
            acc[2][0] += a.z * b.x; acc[2][1] += a.z * b.y; acc[2][2] += a.z * b.z; acc[2][3] += a.z * b.w;
            acc[3][0] += a.w * b.x; acc[3][1] += a.w * b.y; acc[3][2] += a.w * b.z; acc[3][3] += a.w * b.w;
        }

#pragma unroll
        for (int i = 0; i < 4; ++i) {
            int row = row0 + rg * 4 + i;
            if (row < n) {
                float dd = dinv[row];
                pk2 p;
                p.h[0] = __floats2half2_rn(acc[i][0] * dd, acc[i][1] * dd);
                p.h[1] = __floats2half2_rn(acc[i][2] * dd, acc[i][3] * dd);
                *(uint2*)&h2[(size_t)row * 40 + tc * 4] = p.u;
            }
        }
    }
}

// ---------------- gathers: bucket-block LDS-atomic accumulate ----------------

// agg1[d] = (sum_{s in in(d)} hs[s] + hs[d]) * dinv[d] + b1 (hs pre-scaled).
// Block per bucket; 32 groups x 8 lanes; lane loads uint4 (8 fp16 features).
__global__ __launch_bounds__(256) void k_gather1_lds(const int* __restrict__ pairs,
                                                     const int* __restrict__ bbase,
                                                     const __half* __restrict__ hs,
                                                     const float* __restrict__ dinv,
                                                     const float* __restrict__ b1,
                                                     __half* __restrict__ agg1, int n) {
    __shared__ float acc[NPB * 66];
    int t = threadIdx.x;
    for (int i = t; i < NPB * 66; i += 256) acc[i] = 0.f;
    __syncthreads();
    int bid = blockIdx.x;
    int node0 = bid << NB_SHIFT;
    int ebeg = bbase[bid], eend = bbase[bid + 1];
    int g = t >> 3;     // 32 edge groups
    int q = t & 7;      // feature quad (8 fp16 = 16B)
    int j = ebeg + g;
    for (; j + 32 < eend; j += 64) {
        int pkA = pairs[j];
        int pkB = pairs[j + 32];
        int sA = pkA & 0x1FFFF, ldA = pkA >> 17;
        int sB = pkB & 0x1FFFF, ldB = pkB >> 17;
        uint4 uA = *(const uint4*)(hs + ((size_t)sA << 6) + (q << 3));
        uint4 uB = *(const uint4*)(hs + ((size_t)sB << 6) + (q << 3));
        acc8(&acc[ldA * 66 + q * 8], uA);
        acc8(&acc[ldB * 66 + q * 8], uB);
    }
    for (; j < eend; j += 32) {
        int pk = pairs[j];
        int s = pk & 0x1FFFF, ld = pk >> 17;
        uint4 u = *(const uint4*)(hs + ((size_t)s << 6) + (q << 3));
        acc8(&acc[ld * 66 + q * 8], u);
    }
    __syncthreads();
    // epilogue: 4 features per item, coalesced uint2 stores
    for (int i = t; i < NPB * 16; i += 256) {
        int ld = i >> 4, qq = i & 15;
        int node = node0 + ld;
        if (node < n) {
            float dd = dinv[node];
            const float* a = &acc[ld * 66 + qq * 4];
            uint2 us = *(const uint2*)(hs + ((size_t)node << 6) + (qq << 2));
            __half2 s0 = *(__half2*)&us.x, s1 = *(__half2*)&us.y;
            float2 g0 = __half22float2(s0), g1 = __half22float2(s1);
            float4 b = *(const float4*)(b1 + qq * 4);
            pk2 p;
            p.h[0] = __floats2half2_rn((a[0] + g0.x) * dd + b.x,
                                       (a[1] + g0.y) * dd + b.y);
            p.h[1] = __floats2half2_rn((a[2] + g1.x) * dd + b.z,
                                       (a[3] + g1.y) * dd + b.w);
            *(uint2*)&agg1[(size_t)node * 64 + qq * 4] = p.u;
        }
    }
}

// out[d] = (sum h2s[s] + h2s[d]) * dinv[d] + b2, fp32 out.
// 51 groups x 5 lanes (t<255); lane loads uint4 (8 fp16 of 40).
__global__ __launch_bounds__(256) void k_gather2_lds(const int* __restrict__ pairs,
                                                     const int* __restrict__ bbase,
                                                     const __half* __restrict__ h2s,
                                                     const float* __restrict__ dinv,
                                                     const float* __restrict__ b2,
                                                     float* __restrict__ out, int n) {
    __shared__ float acc[NPB * 42];
    int t = threadIdx.x;
    for (int i = t; i < NPB * 42; i += 256) acc[i] = 0.f;
    __syncthreads();
    int bid = blockIdx.x;
    int node0 = bid << NB_SHIFT;
    int ebeg = bbase[bid], eend = bbase[bid + 1];
    int g = t / 5;
    int q = t - g * 5;
    if (t < 255) {
        int j = ebeg + g;
        for (; j + 51 < eend; j += 102) {
            int pkA = pairs[j];
            int pkB = pairs[j + 51];
            int sA = pkA & 0x1FFFF, ldA = pkA >> 17;
            int sB = pkB & 0x1FFFF, ldB = pkB >> 17;
            uint4 uA = *(const uint4*)(h2s + (size_t)sA * 40 + q * 8);
            uint4 uB = *(const uint4*)(h2s + (size_t)sB * 40 + q * 8);
            acc8(&acc[ldA * 42 + q * 8], uA);
            acc8(&acc[ldB * 42 + q * 8], uB);
        }
        for (; j < eend; j += 51) {
            int pk = pairs[j];
            int s = pk & 0x1FFFF, ld = pk >> 17;
            uint4 u = *(const uint4*)(h2s + (size_t)s * 40 + q * 8);
            acc8(&acc[ld * 42 + q * 8], u);
        }
    }
    __syncthreads();
    // epilogue: float4 per item (10 quads per node)
    for (int i = t; i < NPB * 10; i += 256) {
        int ld = i / 10, qq = i - ld * 10;
        int node = node0 + ld;
        if (node < n) {
            float dd = dinv[node];
            const float* a = &acc[ld * 42 + qq * 4];
            uint2 us = *(const uint2*)(h2s + (size_t)node * 40 + qq * 4);
            __half2 s0 = *(__half2*)&us.x, s1 = *(__half2*)&us.y;
            float2 g0 = __half22float2(s0), g1 = __half22float2(s1);
            float4 b = *(const float4*)(b2 + qq * 4);
            float4 o;
            o.x = (a[0] + g0.x) * dd + b.x;
            o.y = (a[1] + g0.y) * dd + b.y;
            o.z = (a[2] + g1.x) * dd + b.z;
            o.w = (a[3] + g1.y) * dd + b.w;
            *(float4*)&out[(size_t)node * 40 + qq * 4] = o;
        }
    }
}

// ---------------- fallback atomic-scatter path (fp32, proven) ----------------

__global__ void k_init_deg(float* __restrict__ deg, int n) {
    int i = blockIdx.x * blockDim.x + threadIdx.x;
    if (i < n) deg[i] = 1.0f;
}

__global__ void k_deg(const int* __restrict__ dst, int E, float* __restrict__ deg) {
    int i = blockIdx.x * blockDim.x + threadIdx.x;
    if (i < E) atomicAdd(&deg[dst[i]], 1.0f);
}

__global__ void k_rsqrt(float* __restrict__ deg, int n) {
    int i = blockIdx.x * blockDim.x + threadIdx.x;
    if (i < n) deg[i] = rsqrtf(deg[i]);
}

__global__ __launch_bounds__(256) void k_gemm1_f(const float* __restrict__ x,
                                                 const float* __restrict__ W,
                                                 float* __restrict__ h, int n) {
    __shared__ float Ws[128 * 64];
    __shared__ float xsT[128 * 64];
    const int tid = threadIdx.x;
    const int row0 = blockIdx.x * 64;
    {
        const float4* Wg = (const float4*)W;
        float4* Wl = (float4*)Ws;
#pragma unroll
        for (int t = 0; t < 8; ++t) Wl[tid + t * 256] = Wg[tid + t * 256];
    }
    {
        int r = tid & 63, g = tid >> 6;
        int row = row0 + r;
        const float4* xr = (const float4*)(x + (size_t)row * 128);
#pragma unroll
        for (int t = 0; t < 8; ++t) {
            int k0 = g * 32 + t * 4;
            float4 v = (row < n) ? xr[k0 >> 2] : make_float4(0.f, 0.f, 0.f, 0.f);
            xsT[(k0 + 0) * 64 + r] = v.x;
            xsT[(k0 + 1) * 64 + r] = v.y;
            xsT[(k0 + 2) * 64 + r] = v.z;
            xsT[(k0 + 3) * 64 + r] = v.w;
        }
    }
    __syncthreads();
    const int tc = tid & 15;
    const int rg = tid >> 4;
    float acc[4][4];
#pragma unroll
    for (int i = 0; i < 4; ++i)
#pragma unroll
        for (int j = 0; j < 4; ++j) acc[i][j] = 0.f;
#pragma unroll 4
    for (int k = 0; k < 128; ++k) {
        float4 a = *(const float4*)&xsT[k * 64 + rg * 4];
        float4 b = *(const float4*)&Ws[k * 64 + tc * 4];
        acc[0][0] += a.x * b.x; acc[0][1] += a.x * b.y; acc[0][2] += a.x * b.z; acc[0][3] += a.x * b.w;
        acc[1][0] += a.y * b.x; acc[1][1] += a.y * b.y; acc[1][2] += a.y * b.z; acc[1][3] += a.y * b.w;
        acc[2][0] += a.z * b.x; acc[2][1] += a.z * b.y; acc[2][2] += a.z * b.z; acc[2][3] += a.z * b.w;
        acc[3][0] += a.w * b.x; acc[3][1] += a.w * b.y; acc[3][2] += a.w * b.z; acc[3][3] += a.w * b.w;
    }
#pragma unroll
    for (int i = 0; i < 4; ++i) {
        int row = row0 + rg * 4 + i;
        if (row < n)
            *(float4*)&h[(size_t)row * 64 + tc * 4] =
                make_float4(acc[i][0], acc[i][1], acc[i][2], acc[i][3]);
    }
}

__global__ __launch_bounds__(256) void k_gemm2_f(const float* __restrict__ agg,
                                                 const float* __restrict__ W2,
                                                 float* __restrict__ h2, int n) {
    __shared__ float Ws[64 * 40];
    __shared__ float hsT[64 * 64];
    const int tid = threadIdx.x;
    const int row0 = blockIdx.x * 64;
    {
        const float4* Wg = (const float4*)W2;
        float4* Wl = (float4*)Ws;
        for (int i = tid; i < 640; i += 256) Wl[i] = Wg[i];
    }
    {
        int r = tid & 63, g = tid >> 6;
        int row = row0 + r;
        const float4* ar = (const float4*)(agg + (size_t)row * 64);
#pragma unroll
        for (int t = 0; t < 4; ++t) {
            int k0 = g * 16 + t * 4;
            float4 v = (row < n) ? ar[k0 >> 2] : make_float4(0.f, 0.f, 0.f, 0.f);
            hsT[(k0 + 0) * 64 + r] = v.x > 0.f ? v.x : 0.f;
            hsT[(k0 + 1) * 64 + r] = v.y > 0.f ? v.y : 0.f;
            hsT[(k0 + 2) * 64 + r] = v.z > 0.f ? v.z : 0.f;
            hsT[(k0 + 3) * 64 + r] = v.w > 0.f ? v.w : 0.f;
        }
    }
    __syncthreads();
    const int tc = tid & 15;
    const int rg = tid >> 4;
    if (tc < 10) {
        float acc[4][4];
#pragma unroll
        for (int i = 0; i < 4; ++i)
#pragma unroll
            for (int j = 0; j < 4; ++j) acc[i][j] = 0.f;
#pragma unroll 4
        for (int k = 0; k < 64; ++k) {
            float4 a = *(const float4*)&hsT[k * 64 + rg * 4];
            float4 b = *(const float4*)&Ws[k * 40 + tc * 4];
            acc[0][0] += a.x * b.x; acc[0][1] += a.x * b.y; acc[0][2] += a.x * b.z; acc[0][3] += a.x * b.w;
            acc[1][0] += a.y * b.x; acc[1][1] += a.y * b.y; acc[1][2] += a.y * b.z; acc[1][3] += a.y * b.w;
            acc[2][0] += a.z * b.x; acc[2][1] += a.z * b.y; acc[2][2] += a.z * b.z; acc[2][3] += a.z * b.w;
            acc[3][0] += a.w * b.x; acc[3][1] += a.w * b.y; acc[3][2] += a.w * b.z; acc[3][3] += a.w * b.w;
        }
#pragma unroll
        for (int i = 0; i < 4; ++i) {
            int row = row0 + rg * 4 + i;
            if (row < n)
                *(float4*)&h2[(size_t)row * 40 + tc * 4] =
                    make_float4(acc[i][0], acc[i][1], acc[i][2], acc[i][3]);
        }
    }
}

__global__ void k_init_agg1(const float* __restrict__ h, const float* __restrict__ dinv,
                            const float* __restrict__ b1, float* __restrict__ agg, int n) {
    int idx = blockIdx.x * blockDim.x + threadIdx.x;
    if (idx < n * 64) {
        int i = idx >> 6, f = idx & 63;
        float d = dinv[i];
        agg[idx] = h[idx] * d * d + b1[f];
    }
}

__global__ __launch_bounds__(256) void k_scatter1(const float* __restrict__ h,
                                                  const int* __restrict__ src,
                                                  const int* __restrict__ dst,
                                                  const float* __restrict__ dinv,
                                                  float* __restrict__ agg, int E) {
    int e = blockIdx.x * 4 + (threadIdx.x >> 6);
    if (e >= E) return;
    int f = threadIdx.x & 63;
    int s = src[e], d = dst[e];
    float w = dinv[s] * dinv[d];
    atomicAdd(&agg[d * 64 + f], h[s * 64 + f] * w);
}

__global__ void k_init_out(const float* __restrict__ h2, const float* __restrict__ dinv,
                           const float* __restrict__ b2, float* __restrict__ out, int n) {
    int idx = blockIdx.x * blockDim.x + threadIdx.x;
    if (idx < n * 40) {
        int i = idx / 40;
        int f = idx - i * 40;
        float d = dinv[i];
        out[idx] = h2[idx] * d * d + b2[f];
    }
}

__global__ __launch_bounds__(256) void k_scatter2(const float* __restrict__ h2,
                                                  const int* __restrict__ src,
                                                  const int* __restrict__ dst,
                                                  const float* __restrict__ dinv,
                                                  float* __restrict__ out, int E) {
    int idx = blockIdx.x * blockDim.x + threadIdx.x;
    int total = E * 40;
    if (idx >= total) return;
    int e = idx / 40;
    int f = idx - e * 40;
    int s = src[e], d = dst[e];
    float w = dinv[s] * dinv[d];
    atomicAdd(&out[d * 40 + f], h2[s * 40 + f] * w);
}

extern "C" void kernel_launch(void* const* d_in, const int* in_sizes, int n_in,
                              void* d_out, int out_size, void* d_ws, size_t ws_size,
                              hipStream_t stream) {
    const float* x  = (const float*)d_in[0];
    const int*   ei = (const int*)d_in[1];
    const float* W1 = (const float*)d_in[2];
    const float* b1 = (const float*)d_in[3];
    const float* W2 = (const float*)d_in[4];
    const float* b2 = (const float*)d_in[5];
    float* out = (float*)d_out;

    const int n = in_sizes[0] / 128;   // 100000
    const int E = in_sizes[1] / 2;     // 1600000
    const int* src = ei;
    const int* dst = ei + E;

    char* ws = (char*)d_ws;
    const size_t MB = 1 << 20;
    float*  dinv   = (float*)(ws);                       // n floats
    int*    bbase  = (int*)  (ws + 512 * 1024);          // NBCAP+1 ints
    int*    bcnt   = (int*)  (ws + 544 * 1024);          // NBCAP ints
    int*    bcur   = (int*)  (ws + 576 * 1024);          // NBCAP ints
    __half* hs_h   = (__half*)(ws + 2 * MB);             // n*64 halves (12.8MB)
    __half* agg1_h = (__half*)(ws + 15 * MB);            // n*64 halves (12.8MB)
    __half* h2s_h  = hs_h;                               // reuse (hs dead after gemm2)
    int*    pairs  = (int*)  (ws + 28 * MB);             // E ints
    size_t needed_fast = 28 * MB + (size_t)E * 4;

    const int nb = (n + NPB - 1) / NPB;

    if (ws_size >= needed_fast && nb <= NBCAP && n <= 131072 && E >= 1024) {
        // ---- bucket partition ----
        int epb = (E + 1023) / 1024;                     // edges per binpass block
        k_zero<<<(nb + 255) / 256, 256, 0, stream>>>(bcnt, nb);
        k_hist<<<512, 256, 0, stream>>>(dst, E, bcnt, nb);
        k_scan_nb<<<1, 1024, 0, stream>>>(bcnt, bbase, bcur, nb);
        k_binpass<<<1024, 256, 0, stream>>>(src, dst, bcur, pairs, nb, E, epb);
        k_bucket_deg<<<nb, 256, 0, stream>>>(pairs, bbase, dinv, n);

        // ---- layer 1 ----
        k_gemm1_h<<<(n + 63) / 64, 256, 0, stream>>>(x, W1, hs_h, n, dinv);
        k_gather1_lds<<<nb, 256, 0, stream>>>(pairs, bbase, hs_h, dinv, b1, agg1_h, n);

        // ---- layer 2 ----
        k_gemm2_h<<<(n + 63) / 64, 256, 0, stream>>>(agg1_h, W2, h2s_h, n, dinv);
        k_gather2_lds<<<nb, 256, 0, stream>>>(pairs, bbase, h2s_h, dinv, b2, out, n);
    } else {
        // ---- fallback: fp32 atomic scatter path ----
        float* hlin = (float*)(ws + 2 * MB);
        float* agg1 = (float*)(ws + 28 * MB);
        k_init_deg<<<(n + 255) / 256, 256, 0, stream>>>(dinv, n);
        k_deg<<<(E + 255) / 256, 256, 0, stream>>>(dst, E, dinv);
        k_rsqrt<<<(n + 255) / 256, 256, 0, stream>>>(dinv, n);
        k_gemm1_f<<<(n + 63) / 64, 256, 0, stream>>>(x, W1, hlin, n);
        k_init_agg1<<<(n * 64 + 255) / 256, 256, 0, stream>>>(hlin, dinv, b1, agg1, n);
        k_scatter1<<<(E + 3) / 4, 256, 0, stream>>>(hlin, src, dst, dinv, agg1, E);
        k_gemm2_f<<<(n + 63) / 64, 256, 0, stream>>>(agg1, W2, hlin, n);
        k_init_out<<<(n * 40 + 255) / 256, 256, 0, stream>>>(hlin, dinv, b2, out, n);
        int total2 = E * 40;
        k_scatter2<<<(total2 + 255) / 256, 256, 0, stream>>>(hlin, src, dst, dinv, out, E);
    }
}

// Round 7
// 199.161 us; speedup vs baseline: 5.5191x; 5.5191x over previous
//
#include <hip/hip_runtime.h>
#include <hip/hip_fp16.h>

// ---------------------------------------------------------------------------
// GCN 2-layer forward: out = A_hat @ relu(A_hat @ (x@W1) + b1) @ W2 + b2
// A_hat = D^-1/2 (A + I) D^-1/2.
// CSC via locality-aware counting sort (round-5 proven); gathers are
// persistent grid-stride waves with uint4 fp16 row loads + shfl reduce.
// Intermediates fp16, fp32 accumulate. (Round-6 LDS-atomic gather reverted:
// LDS float atomics serialize badly on gfx950 -> 12x regression.)
// ---------------------------------------------------------------------------

#define NPB   128     // nodes per coarse bucket
#define NBCAP 1024    // max buckets supported by fast path

// ---------------- CSC build ----------------

__global__ void k_zero(int* __restrict__ p, int m) {
    int i = blockIdx.x * blockDim.x + threadIdx.x;
    if (i < m) p[i] = 0;
}

__global__ __launch_bounds__(256) void k_hist(const int* __restrict__ dst, int E,
                                              int* __restrict__ bcnt, int nb) {
    __shared__ int h[NBCAP];
    for (int i = threadIdx.x; i < nb; i += 256) h[i] = 0;
    __syncthreads();
    int stride = gridDim.x * 256;
    for (int e = blockIdx.x * 256 + threadIdx.x; e < E; e += stride)
        atomicAdd(&h[dst[e] >> 7], 1);
    __syncthreads();
    for (int i = threadIdx.x; i < nb; i += 256)
        if (h[i]) atomicAdd(&bcnt[i], h[i]);
}

__global__ __launch_bounds__(1024) void k_scan_nb(const int* __restrict__ bcnt,
                                                  int* __restrict__ bbase,
                                                  int* __restrict__ bcur, int nb) {
    __shared__ int tmp[NBCAP];
    int t = threadIdx.x;
    int v = (t < nb) ? bcnt[t] : 0;
    tmp[t] = v;
    __syncthreads();
    for (int ofs = 1; ofs < NBCAP; ofs <<= 1) {
        int u = (t >= ofs) ? tmp[t - ofs] : 0;
        __syncthreads();
        if (t >= ofs) tmp[t] += u;
        __syncthreads();
    }
    if (t < nb) {
        int ex = tmp[t] - v;
        bbase[t] = ex;
        bcur[t] = ex;
        if (t == nb - 1) bbase[nb] = tmp[t];
    }
}

__global__ __launch_bounds__(256) void k_binpass(const int* __restrict__ src,
                                                 const int* __restrict__ dst,
                                                 int* __restrict__ bcur,
                                                 int* __restrict__ pairs,
                                                 int nb, int E) {
    __shared__ int lh[NBCAP];
    __shared__ int lbase[NBCAP];
    for (int i = threadIdx.x; i < nb; i += 256) lh[i] = 0;
    __syncthreads();
    int base = blockIdx.x * 4096;
    int pk[16], bb[16];
#pragma unroll
    for (int k = 0; k < 16; ++k) {
        int e = base + k * 256 + threadIdx.x;
        if (e < E) {
            int d = dst[e];
            int b = d >> 7;
            bb[k] = b;
            pk[k] = src[e] | ((d & (NPB - 1)) << 17);
            atomicAdd(&lh[b], 1);
        } else bb[k] = -1;
    }
    __syncthreads();
    for (int i = threadIdx.x; i < nb; i += 256) {
        int c = lh[i];
        lbase[i] = c ? atomicAdd(&bcur[i], c) : 0;
        lh[i] = 0;
    }
    __syncthreads();
#pragma unroll
    for (int k = 0; k < 16; ++k) {
        if (bb[k] >= 0) {
            int r = atomicAdd(&lh[bb[k]], 1);
            pairs[lbase[bb[k]] + r] = pk[k];
        }
    }
}

__global__ __launch_bounds__(256) void k_bucket_build(const int* __restrict__ pairs,
                                                      const int* __restrict__ bbase,
                                                      int* __restrict__ off,
                                                      int* __restrict__ csrc,
                                                      float* __restrict__ dinv,
                                                      int n, int nb) {
    __shared__ int deg[NPB], sc[NPB], cur[NPB];
    int t = threadIdx.x;
    int bid = blockIdx.x;
    int node0 = bid * NPB;
    int ebeg = bbase[bid], eend = bbase[bid + 1];
    if (t < NPB) deg[t] = 0;
    __syncthreads();
    for (int e = ebeg + t; e < eend; e += 256)
        atomicAdd(&deg[pairs[e] >> 17], 1);
    __syncthreads();
    if (t < NPB) sc[t] = deg[t];
    __syncthreads();
    for (int ofs = 1; ofs < NPB; ofs <<= 1) {
        int u = (t < NPB && t >= ofs) ? sc[t - ofs] : 0;
        __syncthreads();
        if (t < NPB && t >= ofs) sc[t] += u;
        __syncthreads();
    }
    if (t < NPB) {
        int ex = sc[t] - deg[t];
        cur[t] = ex;
        int node = node0 + t;
        if (node < n) {
            off[node] = ebeg + ex;
            dinv[node] = rsqrtf((float)(deg[t] + 1));
        }
    }
    if (t == 0 && bid == nb - 1) off[n] = eend;
    __syncthreads();
    for (int e = ebeg + t; e < eend; e += 256) {
        int pkv = pairs[e];
        int r = atomicAdd(&cur[pkv >> 17], 1);
        csrc[ebeg + r] = pkv & 0x1FFFF;
    }
}

// ---------------- helpers ----------------

union pk2 { __half2 h[2]; uint2 u; };
union pk4 { __half2 h[4]; uint4 u; };

#define F4ADD(a, b) { (a).x += (b).x; (a).y += (b).y; (a).z += (b).z; (a).w += (b).w; }

// unpack uint4 (8 fp16) and accumulate into two float4s
__device__ __forceinline__ void acc8f(float4& lo, float4& hi, uint4 u) {
    __half2 h0 = *(__half2*)&u.x, h1 = *(__half2*)&u.y;
    __half2 h2v = *(__half2*)&u.z, h3v = *(__half2*)&u.w;
    float2 f0 = __half22float2(h0), f1 = __half22float2(h1);
    float2 f2 = __half22float2(h2v), f3 = __half22float2(h3v);
    lo.x += f0.x; lo.y += f0.y; lo.z += f1.x; lo.w += f1.y;
    hi.x += f2.x; hi.y += f2.y; hi.z += f3.x; hi.w += f3.y;
}

// guarded butterfly step: lanes with act add shfl_down(delta) into acc
__device__ __forceinline__ void redstep(float4& lo, float4& hi, int delta, bool act) {
    float4 rl, rh;
    rl.x = __shfl_down(lo.x, delta); rl.y = __shfl_down(lo.y, delta);
    rl.z = __shfl_down(lo.z, delta); rl.w = __shfl_down(lo.w, delta);
    rh.x = __shfl_down(hi.x, delta); rh.y = __shfl_down(hi.y, delta);
    rh.z = __shfl_down(hi.z, delta); rh.w = __shfl_down(hi.w, delta);
    if (act) { F4ADD(lo, rl); F4ADD(hi, rh); }
}

// ---------------- dense layers (fp16 out, register-tiled) ----------------

__global__ __launch_bounds__(256) void k_gemm1_h(const float* __restrict__ x,
                                                 const float* __restrict__ W,
                                                 __half* __restrict__ h, int n,
                                                 const float* __restrict__ dinv) {
    __shared__ float Ws[128 * 64];
    __shared__ float xsT[128 * 64];
    const int tid = threadIdx.x;
    const int row0 = blockIdx.x * 64;
    {
        const float4* Wg = (const float4*)W;
        float4* Wl = (float4*)Ws;
#pragma unroll
        for (int t = 0; t < 8; ++t) Wl[tid + t * 256] = Wg[tid + t * 256];
    }
    {
        int r = tid & 63, g = tid >> 6;
        int row = row0 + r;
        const float4* xr = (const float4*)(x + (size_t)row * 128);
#pragma unroll
        for (int t = 0; t < 8; ++t) {
            int k0 = g * 32 + t * 4;
            float4 v = (row < n) ? xr[k0 >> 2] : make_float4(0.f, 0.f, 0.f, 0.f);
            xsT[(k0 + 0) * 64 + r] = v.x;
            xsT[(k0 + 1) * 64 + r] = v.y;
            xsT[(k0 + 2) * 64 + r] = v.z;
            xsT[(k0 + 3) * 64 + r] = v.w;
        }
    }
    __syncthreads();

    const int tc = tid & 15;
    const int rg = tid >> 4;
    float acc[4][4];
#pragma unroll
    for (int i = 0; i < 4; ++i)
#pragma unroll
        for (int j = 0; j < 4; ++j) acc[i][j] = 0.f;

#pragma unroll 4
    for (int k = 0; k < 128; ++k) {
        float4 a = *(const float4*)&xsT[k * 64 + rg * 4];
        float4 b = *(const float4*)&Ws[k * 64 + tc * 4];
        acc[0][0] += a.x * b.x; acc[0][1] += a.x * b.y; acc[0][2] += a.x * b.z; acc[0][3] += a.x * b.w;
        acc[1][0] += a.y * b.x; acc[1][1] += a.y * b.y; acc[1][2] += a.y * b.z; acc[1][3] += a.y * b.w;
        acc[2][0] += a.z * b.x; acc[2][1] += a.z * b.y; acc[2][2] += a.z * b.z; acc[2][3] += a.z * b.w;
        acc[3][0] += a.w * b.x; acc[3][1] += a.w * b.y; acc[3][2] += a.w * b.z; acc[3][3] += a.w * b.w;
    }

#pragma unroll
    for (int i = 0; i < 4; ++i) {
        int row = row0 + rg * 4 + i;
        if (row < n) {
            float dd = dinv[row];
            pk2 p;
            p.h[0] = __floats2half2_rn(acc[i][0] * dd, acc[i][1] * dd);
            p.h[1] = __floats2half2_rn(acc[i][2] * dd, acc[i][3] * dd);
            *(uint2*)&h[(size_t)row * 64 + tc * 4] = p.u;
        }
    }
}

__global__ __launch_bounds__(256) void k_gemm2_h(const __half* __restrict__ agg,
                                                 const float* __restrict__ W2,
                                                 __half* __restrict__ h2, int n,
                                                 const float* __restrict__ dinv) {
    __shared__ float Ws[64 * 40];
    __shared__ float hsT[64 * 64];
    const int tid = threadIdx.x;
    const int row0 = blockIdx.x * 64;
    {
        const float4* Wg = (const float4*)W2;
        float4* Wl = (float4*)Ws;
        for (int i = tid; i < 640; i += 256) Wl[i] = Wg[i];
    }
    {
        int r = tid & 63, g = tid >> 6;
        int row = row0 + r;
        const __half* ar = agg + (size_t)row * 64;
#pragma unroll
        for (int t = 0; t < 4; ++t) {
            int k0 = g * 16 + t * 4;
            float4 v = make_float4(0.f, 0.f, 0.f, 0.f);
            if (row < n) {
                uint2 u = *(const uint2*)(ar + k0);
                __half2 h0 = *(__half2*)&u.x, h1 = *(__half2*)&u.y;
                float2 f0 = __half22float2(h0), f1 = __half22float2(h1);
                v = make_float4(f0.x, f0.y, f1.x, f1.y);
            }
            hsT[(k0 + 0) * 64 + r] = v.x > 0.f ? v.x : 0.f;
            hsT[(k0 + 1) * 64 + r] = v.y > 0.f ? v.y : 0.f;
            hsT[(k0 + 2) * 64 + r] = v.z > 0.f ? v.z : 0.f;
            hsT[(k0 + 3) * 64 + r] = v.w > 0.f ? v.w : 0.f;
        }
    }
    __syncthreads();

    const int tc = tid & 15;
    const int rg = tid >> 4;
    if (tc < 10) {
        float acc[4][4];
#pragma unroll
        for (int i = 0; i < 4; ++i)
#pragma unroll
            for (int j = 0; j < 4; ++j) acc[i][j] = 0.f;

#pragma unroll 4
        for (int k = 0; k < 64; ++k) {
            float4 a = *(const float4*)&hsT[k * 64 + rg * 4];
            float4 b = *(const float4*)&Ws[k * 40 + tc * 4];
            acc[0][0] += a.x * b.x; acc[0][1] += a.x * b.y; acc[0][2] += a.x * b.z; acc[0][3] += a.x * b.w;
            acc[1][0] += a.y * b.x; acc[1][1] += a.y * b.y; acc[1][2] += a.y * b.z; acc[1][3] += a.y * b.w;
            acc[2][0] += a.z * b.x; acc[2][1] += a.z * b.y; acc[2][2] += a.z * b.z; acc[2][3] += a.z * b.w;
            acc[3][0] += a.w * b.x; acc[3][1] += a.w * b.y; acc[3][2] += a.w * b.z; acc[3][3] += a.w * b.w;
        }

#pragma unroll
        for (int i = 0; i < 4; ++i) {
            int row = row0 + rg * 4 + i;
            if (row < n) {
                float dd = dinv[row];
                pk2 p;
                p.h[0] = __floats2half2_rn(acc[i][0] * dd, acc[i][1] * dd);
                p.h[1] = __floats2half2_rn(acc[i][2] * dd, acc[i][3] * dd);
                *(uint2*)&h2[(size_t)row * 40 + tc * 4] = p.u;
            }
        }
    }
}

// ---------------- gathers: persistent waves, uint4 loads, shfl reduce -------

// agg1[d] = (sum_{s in in(d)} hs[s] + hs[d]) * dinv[d] + b1 (hs pre-scaled).
// Wave per node (grid-stride); 8 edge-groups x 8 lanes; lane loads uint4
// (8 fp16 feats); 16 edges in flight; 3-step guarded shfl reduce.
__global__ __launch_bounds__(256) void k_gather1_h(const __half* __restrict__ hs,
                                                   const int* __restrict__ off,
                                                   const int* __restrict__ csrc,
                                                   const float* __restrict__ dinv,
                                                   const float* __restrict__ bias1,
                                                   __half* __restrict__ agg1,
                                                   int n, int nwaves) {
    int wid = (blockIdx.x * 256 + threadIdx.x) >> 6;
    int lane = threadIdx.x & 63;
    int g = lane >> 3, q = lane & 7;       // edge group / feature quad
    for (int node = wid; node < n; node += nwaves) {
        int beg = off[node], end = off[node + 1];
        float4 a0 = make_float4(0.f, 0.f, 0.f, 0.f);
        float4 a1 = make_float4(0.f, 0.f, 0.f, 0.f);
        float4 c0 = make_float4(0.f, 0.f, 0.f, 0.f);
        float4 c1 = make_float4(0.f, 0.f, 0.f, 0.f);
        int j = beg;
        for (; j + 16 <= end; j += 16) {
            int s0 = csrc[j + g];
            int s1 = csrc[j + 8 + g];
            uint4 u0 = *(const uint4*)(hs + ((size_t)s0 << 6) + (q << 3));
            uint4 u1 = *(const uint4*)(hs + ((size_t)s1 << 6) + (q << 3));
            acc8f(a0, a1, u0);
            acc8f(c0, c1, u1);
        }
        for (; j + 8 <= end; j += 8) {
            int s0 = csrc[j + g];
            uint4 u0 = *(const uint4*)(hs + ((size_t)s0 << 6) + (q << 3));
            acc8f(a0, a1, u0);
        }
        if (j + g < end) {
            int s0 = csrc[j + g];
            uint4 u0 = *(const uint4*)(hs + ((size_t)s0 << 6) + (q << 3));
            acc8f(a0, a1, u0);
        }
        F4ADD(a0, c0); F4ADD(a1, c1);
        redstep(a0, a1, 32, lane < 32);
        redstep(a0, a1, 16, lane < 16);
        redstep(a0, a1, 8,  lane < 8);
        if (lane < 8) {
            float dd = dinv[node];
            uint4 us = *(const uint4*)(hs + ((size_t)node << 6) + (q << 3));
            float4 slo = make_float4(0.f, 0.f, 0.f, 0.f);
            float4 shi = make_float4(0.f, 0.f, 0.f, 0.f);
            acc8f(slo, shi, us);
            float4 blo = *(const float4*)(bias1 + q * 8);
            float4 bhi = *(const float4*)(bias1 + q * 8 + 4);
            pk4 p;
            p.h[0] = __floats2half2_rn((a0.x + slo.x) * dd + blo.x,
                                       (a0.y + slo.y) * dd + blo.y);
            p.h[1] = __floats2half2_rn((a0.z + slo.z) * dd + blo.z,
                                       (a0.w + slo.w) * dd + blo.w);
            p.h[2] = __floats2half2_rn((a1.x + shi.x) * dd + bhi.x,
                                       (a1.y + shi.y) * dd + bhi.y);
            p.h[3] = __floats2half2_rn((a1.z + shi.z) * dd + bhi.z,
                                       (a1.w + shi.w) * dd + bhi.w);
            *(uint4*)&agg1[((size_t)node << 6) + (q << 3)] = p.u;
        }
    }
}

// out[d] = (sum h2s[s] + h2s[d]) * dinv[d] + b2, fp32 out.
// Wave per node (grid-stride); 12 edge-groups x 5 lanes (lanes 60-63 idle);
// lane loads uint4 (8 of 40 fp16 feats); 4-step guarded reduce.
__global__ __launch_bounds__(256) void k_gather2_h(const __half* __restrict__ h2s,
                                                   const int* __restrict__ off,
                                                   const int* __restrict__ csrc,
                                                   const float* __restrict__ dinv,
                                                   const float* __restrict__ b2,
                                                   float* __restrict__ out,
                                                   int n, int nwaves) {
    int wid = (blockIdx.x * 256 + threadIdx.x) >> 6;
    int lane = threadIdx.x & 63;
    int g = lane / 5;
    int q = lane - g * 5;
    bool act = lane < 60;
    for (int node = wid; node < n; node += nwaves) {
        int beg = off[node], end = off[node + 1];
        float4 a0 = make_float4(0.f, 0.f, 0.f, 0.f);
        float4 a1 = make_float4(0.f, 0.f, 0.f, 0.f);
        int j = beg;
        for (; j + 12 <= end; j += 12) {
            if (act) {
                int s0 = csrc[j + g];
                uint4 u0 = *(const uint4*)(h2s + (size_t)s0 * 40 + q * 8);
                acc8f(a0, a1, u0);
            }
        }
        if (act && j + g < end) {
            int s0 = csrc[j + g];
            uint4 u0 = *(const uint4*)(h2s + (size_t)s0 * 40 + q * 8);
            acc8f(a0, a1, u0);
        }
        redstep(a0, a1, 30, lane < 30);
        redstep(a0, a1, 15, lane < 15);
        redstep(a0, a1, 10, lane < 5);
        redstep(a0, a1, 5,  lane < 5);
        if (lane < 5) {
            float dd = dinv[node];
            uint4 us = *(const uint4*)(h2s + (size_t)node * 40 + lane * 8);
            float4 slo = make_float4(0.f, 0.f, 0.f, 0.f);
            float4 shi = make_float4(0.f, 0.f, 0.f, 0.f);
            acc8f(slo, shi, us);
            float4 blo = *(const float4*)(b2 + lane * 8);
            float4 bhi = *(const float4*)(b2 + lane * 8 + 4);
            float4 o0, o1;
            o0.x = (a0.x + slo.x) * dd + blo.x;
            o0.y = (a0.y + slo.y) * dd + blo.y;
            o0.z = (a0.z + slo.z) * dd + blo.z;
            o0.w = (a0.w + slo.w) * dd + blo.w;
            o1.x = (a1.x + shi.x) * dd + bhi.x;
            o1.y = (a1.y + shi.y) * dd + bhi.y;
            o1.z = (a1.z + shi.z) * dd + bhi.z;
            o1.w = (a1.w + shi.w) * dd + bhi.w;
            *(float4*)&out[(size_t)node * 40 + lane * 8] = o0;
            *(float4*)&out[(size_t)node * 40 + lane * 8 + 4] = o1;
        }
    }
}

// ---------------- fallback atomic-scatter path (fp32, proven) ----------------

__global__ void k_init_deg(float* __restrict__ deg, int n) {
    int i = blockIdx.x * blockDim.x + threadIdx.x;
    if (i < n) deg[i] = 1.0f;
}

__global__ void k_deg(const int* __restrict__ dst, int E, float* __restrict__ deg) {
    int i = blockIdx.x * blockDim.x + threadIdx.x;
    if (i < E) atomicAdd(&deg[dst[i]], 1.0f);
}

__global__ void k_rsqrt(float* __restrict__ deg, int n) {
    int i = blockIdx.x * blockDim.x + threadIdx.x;
    if (i < n) deg[i] = rsqrtf(deg[i]);
}

__global__ __launch_bounds__(256) void k_gemm1_f(const float* __restrict__ x,
                                                 const float* __restrict__ W,
                                                 float* __restrict__ h, int n) {
    __shared__ float Ws[128 * 64];
    __shared__ float xsT[128 * 64];
    const int tid = threadIdx.x;
    const int row0 = blockIdx.x * 64;
    {
        const float4* Wg = (const float4*)W;
        float4* Wl = (float4*)Ws;
#pragma unroll
        for (int t = 0; t < 8; ++t) Wl[tid + t * 256] = Wg[tid + t * 256];
    }
    {
        int r = tid & 63, g = tid >> 6;
        int row = row0 + r;
        const float4* xr = (const float4*)(x + (size_t)row * 128);
#pragma unroll
        for (int t = 0; t < 8; ++t) {
            int k0 = g * 32 + t * 4;
            float4 v = (row < n) ? xr[k0 >> 2] : make_float4(0.f, 0.f, 0.f, 0.f);
            xsT[(k0 + 0) * 64 + r] = v.x;
            xsT[(k0 + 1) * 64 + r] = v.y;
            xsT[(k0 + 2) * 64 + r] = v.z;
            xsT[(k0 + 3) * 64 + r] = v.w;
        }
    }
    __syncthreads();
    const int tc = tid & 15;
    const int rg = tid >> 4;
    float acc[4][4];
#pragma unroll
    for (int i = 0; i < 4; ++i)
#pragma unroll
        for (int j = 0; j < 4; ++j) acc[i][j] = 0.f;
#pragma unroll 4
    for (int k = 0; k < 128; ++k) {
        float4 a = *(const float4*)&xsT[k * 64 + rg * 4];
        float4 b = *(const float4*)&Ws[k * 64 + tc * 4];
        acc[0][0] += a.x * b.x; acc[0][1] += a.x * b.y; acc[0][2] += a.x * b.z; acc[0][3] += a.x * b.w;
        acc[1][0] += a.y * b.x; acc[1][1] += a.y * b.y; acc[1][2] += a.y * b.z; acc[1][3] += a.y * b.w;
        acc[2][0] += a.z * b.x; acc[2][1] += a.z * b.y; acc[2][2] += a.z * b.z; acc[2][3] += a.z * b.w;
        acc[3][0] += a.w * b.x; acc[3][1] += a.w * b.y; acc[3][2] += a.w * b.z; acc[3][3] += a.w * b.w;
    }
#pragma unroll
    for (int i = 0; i < 4; ++i) {
        int row = row0 + rg * 4 + i;
        if (row < n)
            *(float4*)&h[(size_t)row * 64 + tc * 4] =
                make_float4(acc[i][0], acc[i][1], acc[i][2], acc[i][3]);
    }
}

__global__ __launch_bounds__(256) void k_gemm2_f(const float* __restrict__ agg,
                                                 const float* __restrict__ W2,
                                                 float* __restrict__ h2, int n) {
    __shared__ float Ws[64 * 40];
    __shared__ float hsT[64 * 64];
    const int tid = threadIdx.x;
    const int row0 = blockIdx.x * 64;
    {
        const float4* Wg = (const float4*)W2;
        float4* Wl = (float4*)Ws;
        for (int i = tid; i < 640; i += 256) Wl[i] = Wg[i];
    }
    {
        int r = tid & 63, g = tid >> 6;
        int row = row0 + r;
        const float4* ar = (const float4*)(agg + (size_t)row * 64);
#pragma unroll
        for (int t = 0; t < 4; ++t) {
            int k0 = g * 16 + t * 4;
            float4 v = (row < n) ? ar[k0 >> 2] : make_float4(0.f, 0.f, 0.f, 0.f);
            hsT[(k0 + 0) * 64 + r] = v.x > 0.f ? v.x : 0.f;
            hsT[(k0 + 1) * 64 + r] = v.y > 0.f ? v.y : 0.f;
            hsT[(k0 + 2) * 64 + r] = v.z > 0.f ? v.z : 0.f;
            hsT[(k0 + 3) * 64 + r] = v.w > 0.f ? v.w : 0.f;
        }
    }
    __syncthreads();
    const int tc = tid & 15;
    const int rg = tid >> 4;
    if (tc < 10) {
        float acc[4][4];
#pragma unroll
        for (int i = 0; i < 4; ++i)
#pragma unroll
            for (int j = 0; j < 4; ++j) acc[i][j] = 0.f;
#pragma unroll 4
        for (int k = 0; k < 64; ++k) {
            float4 a = *(const float4*)&hsT[k * 64 + rg * 4];
            float4 b = *(const float4*)&Ws[k * 40 + tc * 4];
            acc[0][0] += a.x * b.x; acc[0][1] += a.x * b.y; acc[0][2] += a.x * b.z; acc[0][3] += a.x * b.w;
            acc[1][0] += a.y * b.x; acc[1][1] += a.y * b.y; acc[1][2] += a.y * b.z; acc[1][3] += a.y * b.w;
            acc[2][0] += a.z * b.x; acc[2][1] += a.z * b.y; acc[2][2] += a.z * b.z; acc[2][3] += a.z * b.w;
            acc[3][0] += a.w * b.x; acc[3][1] += a.w * b.y; acc[3][2] += a.w * b.z; acc[3][3] += a.w * b.w;
        }
#pragma unroll
        for (int i = 0; i < 4; ++i) {
            int row = row0 + rg * 4 + i;
            if (row < n)
                *(float4*)&h2[(size_t)row * 40 + tc * 4] =
                    make_float4(acc[i][0], acc[i][1], acc[i][2], acc[i][3]);
        }
    }
}

__global__ void k_init_agg1(const float* __restrict__ h, const float* __restrict__ dinv,
                            const float* __restrict__ b1, float* __restrict__ agg, int n) {
    int idx = blockIdx.x * blockDim.x + threadIdx.x;
    if (idx < n * 64) {
        int i = idx >> 6, f = idx & 63;
        float d = dinv[i];
        agg[idx] = h[idx] * d * d + b1[f];
    }
}

__global__ __launch_bounds__(256) void k_scatter1(const float* __restrict__ h,
                                                  const int* __restrict__ src,
                                                  const int* __restrict__ dst,
                                                  const float* __restrict__ dinv,
                                                  float* __restrict__ agg, int E) {
    int e = blockIdx.x * 4 + (threadIdx.x >> 6);
    if (e >= E) return;
    int f = threadIdx.x & 63;
    int s = src[e], d = dst[e];
    float w = dinv[s] * dinv[d];
    atomicAdd(&agg[d * 64 + f], h[s * 64 + f] * w);
}

__global__ void k_init_out(const float* __restrict__ h2, const float* __restrict__ dinv,
                           const float* __restrict__ b2, float* __restrict__ out, int n) {
    int idx = blockIdx.x * blockDim.x + threadIdx.x;
    if (idx < n * 40) {
        int i = idx / 40;
        int f = idx - i * 40;
        float d = dinv[i];
        out[idx] = h2[idx] * d * d + b2[f];
    }
}

__global__ __launch_bounds__(256) void k_scatter2(const float* __restrict__ h2,
                                                  const int* __restrict__ src,
                                                  const int* __restrict__ dst,
                                                  const float* __restrict__ dinv,
                                                  float* __restrict__ out, int E) {
    int idx = blockIdx.x * blockDim.x + threadIdx.x;
    int total = E * 40;
    if (idx >= total) return;
    int e = idx / 40;
    int f = idx - e * 40;
    int s = src[e], d = dst[e];
    float w = dinv[s] * dinv[d];
    atomicAdd(&out[d * 40 + f], h2[s * 40 + f] * w);
}

extern "C" void kernel_launch(void* const* d_in, const int* in_sizes, int n_in,
                              void* d_out, int out_size, void* d_ws, size_t ws_size,
                              hipStream_t stream) {
    const float* x  = (const float*)d_in[0];
    const int*   ei = (const int*)d_in[1];
    const float* W1 = (const float*)d_in[2];
    const float* b1 = (const float*)d_in[3];
    const float* W2 = (const float*)d_in[4];
    const float* b2 = (const float*)d_in[5];
    float* out = (float*)d_out;

    const int n = in_sizes[0] / 128;   // 100000
    const int E = in_sizes[1] / 2;     // 1600000
    const int* src = ei;
    const int* dst = ei + E;

    char* ws = (char*)d_ws;
    const size_t MB = 1 << 20;
    float*  dinv   = (float*)(ws);                       // n floats
    int*    off    = (int*)  (ws + 512 * 1024);          // n+1 ints
    int*    bcnt   = (int*)  (ws + 1 * MB);              // NBCAP ints
    int*    bbase  = (int*)  (ws + 1 * MB + 8 * 1024);   // NBCAP+1 ints
    int*    bcur   = (int*)  (ws + 1 * MB + 16 * 1024);  // NBCAP ints
    __half* hs_h   = (__half*)(ws + 2 * MB);             // n*64 halves (12.8MB)
    __half* agg1_h = (__half*)(ws + 15 * MB);            // n*64 halves (12.8MB)
    __half* h2s_h  = hs_h;                               // reuse (hs dead after gemm2)
    int*    pairs  = (int*)  (ws + 28 * MB);             // E ints
    int*    csrc   = (int*)  (ws + 35 * MB);             // E ints
    size_t needed_fast = 35 * MB + (size_t)E * 4;

    const int nb = (n + NPB - 1) / NPB;

    if (ws_size >= needed_fast && nb <= NBCAP && n <= (1 << 17)) {
        // ---- CSC build via counting sort ----
        k_zero<<<(nb + 255) / 256, 256, 0, stream>>>(bcnt, nb);
        k_hist<<<512, 256, 0, stream>>>(dst, E, bcnt, nb);
        k_scan_nb<<<1, 1024, 0, stream>>>(bcnt, bbase, bcur, nb);
        k_binpass<<<(E + 4095) / 4096, 256, 0, stream>>>(src, dst, bcur, pairs, nb, E);
        k_bucket_build<<<nb, 256, 0, stream>>>(pairs, bbase, off, csrc, dinv, n, nb);

        // ---- layer 1 ----
        const int GB = 2048;                 // persistent gather blocks
        const int NW = GB * 4;               // waves
        k_gemm1_h<<<(n + 63) / 64, 256, 0, stream>>>(x, W1, hs_h, n, dinv);
        k_gather1_h<<<GB, 256, 0, stream>>>(hs_h, off, csrc, dinv, b1, agg1_h, n, NW);

        // ---- layer 2 ----
        k_gemm2_h<<<(n + 63) / 64, 256, 0, stream>>>(agg1_h, W2, h2s_h, n, dinv);
        k_gather2_h<<<GB, 256, 0, stream>>>(h2s_h, off, csrc, dinv, b2, out, n, NW);
    } else {
        // ---- fallback: fp32 atomic scatter path ----
        float* hlin = (float*)(ws + 2 * MB);
        float* agg1 = (float*)(ws + 28 * MB);
        k_init_deg<<<(n + 255) / 256, 256, 0, stream>>>(dinv, n);
        k_deg<<<(E + 255) / 256, 256, 0, stream>>>(dst, E, dinv);
        k_rsqrt<<<(n + 255) / 256, 256, 0, stream>>>(dinv, n);
        k_gemm1_f<<<(n + 63) / 64, 256, 0, stream>>>(x, W1, hlin, n);
        k_init_agg1<<<(n * 64 + 255) / 256, 256, 0, stream>>>(hlin, dinv, b1, agg1, n);
        k_scatter1<<<(E + 3) / 4, 256, 0, stream>>>(hlin, src, dst, dinv, agg1, E);
        k_gemm2_f<<<(n + 63) / 64, 256, 0, stream>>>(agg1, W2, hlin, n);
        k_init_out<<<(n * 40 + 255) / 256, 256, 0, stream>>>(hlin, dinv, b2, out, n);
        int total2 = E * 40;
        k_scatter2<<<(total2 + 255) / 256, 256, 0, stream>>>(hlin, src, dst, dinv, out, E);
    }
}